// Round 2
// baseline (630.704 us; speedup 1.0000x reference)
//
#include <hip/hip_runtime.h>
#include <hip/hip_bf16.h>

#define B_ 8
#define N_ 2048
#define D_ 128

typedef __bf16 bf16_t;
typedef __bf16 v8bf __attribute__((ext_vector_type(8)));
typedef float  v4f  __attribute__((ext_vector_type(4)));
typedef unsigned long long u64;

// ---------------------------------------------------------------------------
// Kernel 1: h = x@W_w + W_b ; g = h@A_w.  One block per (b,n) row.
// ---------------------------------------------------------------------------
__global__ __launch_bounds__(128) void k_hg(
    const float* __restrict__ x, const float* __restrict__ Ww,
    const float* __restrict__ Wb, const float* __restrict__ Aw,
    bf16_t* __restrict__ hb, bf16_t* __restrict__ gb, bf16_t* __restrict__ hbT)
{
    int row = blockIdx.x;          // b*N + n
    int b = row >> 11;
    int n = row & (N_ - 1);
    int j = threadIdx.x;
    __shared__ float xs[D_];
    __shared__ float hs[D_];
    xs[j] = x[(size_t)row * D_ + j];
    __syncthreads();
    float acc = Wb[j];
#pragma unroll 8
    for (int k = 0; k < D_; ++k) acc += xs[k] * Ww[k * D_ + j];
    hs[j] = acc;
    hb[(size_t)row * D_ + j] = (bf16_t)acc;
    hbT[(size_t)b * D_ * N_ + (size_t)j * N_ + n] = (bf16_t)acc;
    __syncthreads();
    float g = 0.f;
#pragma unroll 8
    for (int k = 0; k < D_; ++k) g += hs[k] * Aw[k * D_ + j];
    gb[(size_t)row * D_ + j] = (bf16_t)g;
}

// ---------------------------------------------------------------------------
// Kernel 1b: bit-pack adj. Each thread builds one u64 (64 consecutive cols).
// word idx w covers adj flat [w*64 .. w*64+63]; bit j = adj[w*64+j] > 0.
// ---------------------------------------------------------------------------
__global__ __launch_bounds__(256) void k_pack(
    const float* __restrict__ adj, u64* __restrict__ mask)
{
    size_t widx = (size_t)blockIdx.x * 256 + threadIdx.x;
    const float4* p = (const float4*)(adj + widx * 64);
    u64 m = 0;
#pragma unroll
    for (int i = 0; i < 16; ++i) {
        float4 v = p[i];
        m |= ((u64)(v.x > 0.f)) << (i * 4 + 0);
        m |= ((u64)(v.y > 0.f)) << (i * 4 + 1);
        m |= ((u64)(v.z > 0.f)) << (i * 4 + 2);
        m |= ((u64)(v.w > 0.f)) << (i * 4 + 3);
    }
    mask[widx] = m;
}

// ---------------------------------------------------------------------------
// Kernel 2: colsum[b][m] = sum_n adj[b][n][m] * exp(e[b][n][m]) via bitmask.
// grid: b(8) x mblk(32, 64 cols) x nchunk(8, 256 rows) = 2048 blocks, 4 waves.
// Each block's 64-col span = exactly one u64 mask word per row.
// ---------------------------------------------------------------------------
__global__ __launch_bounds__(256) void k_colsum(
    const bf16_t* __restrict__ hb, const bf16_t* __restrict__ gb,
    const u64* __restrict__ mask, float* __restrict__ colsum)
{
    int bid = blockIdx.x;
    int b = bid >> 8;
    int rem = bid & 255;
    int mblk = rem >> 3;
    int nchunk = rem & 7;
    int wave = threadIdx.x >> 6;
    int lane = threadIdx.x & 63;
    int q = lane >> 4;
    int c = lane & 15;
    int mbase = mblk * 64 + wave * 16;
    const size_t hgoff = (size_t)b * N_ * D_;
    const u64* mb = mask + (size_t)b * N_ * 32;

    v8bf bh[4], bg[4];
#pragma unroll
    for (int kc = 0; kc < 4; ++kc) {
        size_t off = hgoff + (size_t)(mbase + c) * D_ + kc * 32 + q * 8;
        bh[kc] = *(const v8bf*)(hb + off);
        bg[kc] = *(const v8bf*)(gb + off);
    }

    float lsum = 0.f;
    int n0 = nchunk * 256;
    for (int ns = 0; ns < 16; ++ns) {
        int nb = n0 + ns * 16;
        v4f acc = {0.f, 0.f, 0.f, 0.f};
#pragma unroll
        for (int kc = 0; kc < 4; ++kc) {
            size_t off = hgoff + (size_t)(nb + c) * D_ + kc * 32 + q * 8;
            v8bf ag = *(const v8bf*)(gb + off);
            v8bf ah = *(const v8bf*)(hb + off);
            acc = __builtin_amdgcn_mfma_f32_16x16x32_bf16(ag, bh[kc], acc, 0, 0, 0);
            acc = __builtin_amdgcn_mfma_f32_16x16x32_bf16(ah, bg[kc], acc, 0, 0, 0);
        }
#pragma unroll
        for (int r = 0; r < 4; ++r) {
            int nn = nb + q * 4 + r;
            u64 w = mb[nn * 32 + mblk];
            float ex = __expf(acc[r]);
            lsum += ((w >> (wave * 16 + c)) & 1ull) ? ex : 0.f;
        }
    }
    lsum += __shfl_xor(lsum, 16);
    lsum += __shfl_xor(lsum, 32);
    if (lane < 16) atomicAdd(&colsum[b * N_ + mbase + lane], lsum);
}

// ---------------------------------------------------------------------------
// Kernel 3: inv = colsum > 0 ? 1/colsum : 0
// ---------------------------------------------------------------------------
__global__ __launch_bounds__(256) void k_inv(
    const float* __restrict__ cs, float* __restrict__ inv)
{
    int i = blockIdx.x * 256 + threadIdx.x;
    float s = cs[i];
    inv[i] = (s > 0.f) ? 1.f / s : 0.f;
}

// ---------------------------------------------------------------------------
// Kernel 4: partial h_prime = P @ H over an m-half.  P[n,m]=mask*exp(e)*inv[m].
// grid: b(8) x nblk(32) x half(2) = 512 blocks, 512 thr (8 waves).
// wave: wn = n-subtile (16 rows), sh = 512-col sub-half of the 1024-col half.
// Per-wave pbuf -> NO inner barriers. LDS-combine sh pairs, write partial
// to buf0 (half 0) or d_out (half 1).
// ---------------------------------------------------------------------------
__global__ __launch_bounds__(512) void k_out(
    const bf16_t* __restrict__ hb, const bf16_t* __restrict__ gb,
    const bf16_t* __restrict__ hbT, const u64* __restrict__ mask,
    const float* __restrict__ inv, float* __restrict__ buf0,
    float* __restrict__ out)
{
    int bid = blockIdx.x;
    int b = bid >> 6;
    int rem = bid & 63;
    int nblk = rem >> 1;
    int half = rem & 1;
    int tid = threadIdx.x;
    int wave = tid >> 6;
    int lane = tid & 63;
    int q = lane >> 4;
    int c = lane & 15;
    int wn = wave & 3;       // n-subtile
    int sh = wave >> 2;      // 512-col sub-half
    int nbase = nblk * 64 + wn * 16;
    const size_t hgoff = (size_t)b * N_ * D_;

    __shared__ float pbuf[8][16 * 36];   // per-wave P transform buffer
    __shared__ float hp[64][132];        // h_prime combine buffer

    v8bf ag[4], ah[4];
#pragma unroll
    for (int kc = 0; kc < 4; ++kc) {
        size_t off = hgoff + (size_t)(nbase + c) * D_ + kc * 32 + q * 8;
        ag[kc] = *(const v8bf*)(gb + off);
        ah[kc] = *(const v8bf*)(hb + off);
    }

    v4f hpacc[8];
#pragma unroll
    for (int dt = 0; dt < 8; ++dt) hpacc[dt] = (v4f){0.f, 0.f, 0.f, 0.f};

    const u64* mb = mask + (size_t)b * N_ * 32;
    const bf16_t* hTb = hbT + (size_t)b * D_ * N_;
    float* pw = pbuf[wave];
    int mwave = half * 1024 + sh * 512;

    for (int ch = 0; ch < 16; ++ch) {
        int mchunk = mwave + ch * 32;
#pragma unroll
        for (int t = 0; t < 2; ++t) {
            int mt = mchunk + t * 16;
            v4f e = {0.f, 0.f, 0.f, 0.f};
#pragma unroll
            for (int kc = 0; kc < 4; ++kc) {
                size_t off = hgoff + (size_t)(mt + c) * D_ + kc * 32 + q * 8;
                v8bf bh = *(const v8bf*)(hb + off);
                v8bf bg = *(const v8bf*)(gb + off);
                e = __builtin_amdgcn_mfma_f32_16x16x32_bf16(ag[kc], bh, e, 0, 0, 0);
                e = __builtin_amdgcn_mfma_f32_16x16x32_bf16(ah[kc], bg, e, 0, 0, 0);
            }
            float iv = inv[b * N_ + mt + c];
#pragma unroll
            for (int r = 0; r < 4; ++r) {
                int nn = nbase + q * 4 + r;
                u64 w = mb[nn * 32 + (mt >> 6)];
                float ex = __expf(e[r]) * iv;
                float pv = ((w >> ((mt & 63) + c)) & 1ull) ? ex : 0.f;
                pw[(q * 4 + r) * 36 + t * 16 + c] = pv;
            }
        }
        __builtin_amdgcn_wave_barrier();   // wave-local LDS: no block barrier
        v4f p0 = *(const v4f*)&pw[c * 36 + q * 8];
        v4f p1 = *(const v4f*)&pw[c * 36 + q * 8 + 4];
        __builtin_amdgcn_wave_barrier();
        v8bf pf;
#pragma unroll
        for (int j2 = 0; j2 < 4; ++j2) {
            pf[j2]     = (bf16_t)p0[j2];
            pf[j2 + 4] = (bf16_t)p1[j2];
        }
#pragma unroll
        for (int dt = 0; dt < 8; ++dt) {
            const bf16_t* src = hTb + (size_t)(dt * 16 + c) * N_ + mchunk + q * 8;
            v8bf bt = *(const v8bf*)src;
            hpacc[dt] = __builtin_amdgcn_mfma_f32_16x16x32_bf16(pf, bt, hpacc[dt], 0, 0, 0);
        }
    }

    // combine the two sub-halves in LDS
    if (sh == 0) {
#pragma unroll
        for (int dt = 0; dt < 8; ++dt)
#pragma unroll
            for (int r = 0; r < 4; ++r)
                hp[wn * 16 + q * 4 + r][dt * 16 + c] = hpacc[dt][r];
    }
    __syncthreads();
    if (sh == 1) {
#pragma unroll
        for (int dt = 0; dt < 8; ++dt)
#pragma unroll
            for (int r = 0; r < 4; ++r)
                hp[wn * 16 + q * 4 + r][dt * 16 + c] += hpacc[dt][r];
    }
    __syncthreads();

    // write partial h_prime (fp32) for this m-half
    float* pb = (half == 0 ? buf0 : out) + ((size_t)b * N_ + nblk * 64) * D_;
    int row = tid >> 3;
    int seg = tid & 7;
#pragma unroll
    for (int i = 0; i < 4; ++i)
        *(float4*)&pb[row * D_ + seg * 16 + i * 4] =
            *(const float4*)&hp[row][seg * 16 + i * 4];
}

// ---------------------------------------------------------------------------
// Kernel 5: epilogue. hp = relu(buf0+buf1); coeff = sigmoid([x,hp]@gw + gb);
// out = coeff*x + (1-coeff)*hp.  buf1 lives in d_out (overwritten in place).
// One wave per row.
// ---------------------------------------------------------------------------
__global__ __launch_bounds__(256) void k_epi(
    const float* __restrict__ buf0, const float* __restrict__ x,
    const float* __restrict__ gw, const float* __restrict__ gbias,
    float* __restrict__ out)
{
    int row = blockIdx.x * 4 + (threadIdx.x >> 6);
    int lane = threadIdx.x & 63;
    const float* xr = x + (size_t)row * D_;
    const float* b0 = buf0 + (size_t)row * D_;
    float* orow = out + (size_t)row * D_;
    float2 xv = *(const float2*)&xr[lane * 2];
    float2 h0 = *(const float2*)&b0[lane * 2];
    float2 h1 = *(const float2*)&orow[lane * 2];
    float hp0 = fmaxf(h0.x + h1.x, 0.f);
    float hp1 = fmaxf(h0.y + h1.y, 0.f);
    float part = xv.x * gw[lane * 2] + xv.y * gw[lane * 2 + 1]
               + hp0 * gw[D_ + lane * 2] + hp1 * gw[D_ + lane * 2 + 1];
    part += __shfl_xor(part, 1);
    part += __shfl_xor(part, 2);
    part += __shfl_xor(part, 4);
    part += __shfl_xor(part, 8);
    part += __shfl_xor(part, 16);
    part += __shfl_xor(part, 32);
    float coeff = 1.f / (1.f + __expf(-(part + gbias[0])));
    float2 o;
    o.x = coeff * xv.x + (1.f - coeff) * hp0;
    o.y = coeff * xv.y + (1.f - coeff) * hp1;
    *(float2*)&orow[lane * 2] = o;
}

// ---------------------------------------------------------------------------
extern "C" void kernel_launch(void* const* d_in, const int* in_sizes, int n_in,
                              void* d_out, int out_size, void* d_ws, size_t ws_size,
                              hipStream_t stream)
{
    const float* x     = (const float*)d_in[0];
    const float* adj   = (const float*)d_in[1];
    const float* Ww    = (const float*)d_in[2];
    const float* Wb    = (const float*)d_in[3];
    const float* Aw    = (const float*)d_in[4];
    const float* gw    = (const float*)d_in[5];
    const float* gbias = (const float*)d_in[6];
    float* out = (float*)d_out;

    char* ws = (char*)d_ws;
    bf16_t* hb     = (bf16_t*)(ws);                          // 4 MB
    bf16_t* gb     = (bf16_t*)(ws + (4 << 20));              // 4 MB
    bf16_t* hbT    = (bf16_t*)(ws + (8 << 20));              // 4 MB
    float*  colsum = (float*)(ws + (12 << 20));              // 64 KB
    float*  inv    = (float*)(ws + (12 << 20) + (64 << 10)); // 64 KB
    u64*    mask   = (u64*)(ws + (13 << 20));                // 4 MB
    float*  buf0   = (float*)(ws + (17 << 20));              // 8 MB

    hipMemsetAsync(colsum, 0, B_ * N_ * sizeof(float), stream);
    k_hg<<<B_ * N_, 128, 0, stream>>>(x, Ww, Wb, Aw, hb, gb, hbT);
    k_pack<<<B_ * N_ * 32 / 256, 256, 0, stream>>>(adj, mask);
    k_colsum<<<2048, 256, 0, stream>>>(hb, gb, mask, colsum);
    k_inv<<<B_ * N_ / 256, 256, 0, stream>>>(colsum, inv);
    k_out<<<512, 512, 0, stream>>>(hb, gb, hbT, mask, inv, buf0, out);
    k_epi<<<B_ * N_ / 4, 256, 0, stream>>>(buf0, x, gw, gbias, out);
}

// Round 3
// 608.541 us; speedup vs baseline: 1.0364x; 1.0364x over previous
//
#include <hip/hip_runtime.h>
#include <hip/hip_bf16.h>

#define B_ 8
#define N_ 2048
#define D_ 128

typedef __bf16 bf16_t;
typedef __bf16 v8bf __attribute__((ext_vector_type(8)));
typedef float  v4f  __attribute__((ext_vector_type(4)));
typedef unsigned long long u64;

// ---------------------------------------------------------------------------
// Kernel 1: h = x@W_w + W_b ; g = h@A_w.  One block per (b,n) row.
// hb/gb only (hbT moved to k_scaleT — the 2B scatter write was ~150us).
// ---------------------------------------------------------------------------
__global__ __launch_bounds__(128) void k_hg(
    const float* __restrict__ x, const float* __restrict__ Ww,
    const float* __restrict__ Wb, const float* __restrict__ Aw,
    bf16_t* __restrict__ hb, bf16_t* __restrict__ gb)
{
    int row = blockIdx.x;          // b*N + n
    int j = threadIdx.x;
    __shared__ float xs[D_];
    __shared__ float hs[D_];
    xs[j] = x[(size_t)row * D_ + j];
    __syncthreads();
    float a0 = Wb[j], a1 = 0.f, a2 = 0.f, a3 = 0.f;
#pragma unroll 8
    for (int k = 0; k < D_; k += 4) {
        a0 += xs[k]     * Ww[(k)     * D_ + j];
        a1 += xs[k + 1] * Ww[(k + 1) * D_ + j];
        a2 += xs[k + 2] * Ww[(k + 2) * D_ + j];
        a3 += xs[k + 3] * Ww[(k + 3) * D_ + j];
    }
    float acc = (a0 + a1) + (a2 + a3);
    hs[j] = acc;
    hb[(size_t)row * D_ + j] = (bf16_t)acc;
    __syncthreads();
    float g0 = 0.f, g1 = 0.f, g2 = 0.f, g3 = 0.f;
#pragma unroll 8
    for (int k = 0; k < D_; k += 4) {
        g0 += hs[k]     * Aw[(k)     * D_ + j];
        g1 += hs[k + 1] * Aw[(k + 1) * D_ + j];
        g2 += hs[k + 2] * Aw[(k + 2) * D_ + j];
        g3 += hs[k + 3] * Aw[(k + 3) * D_ + j];
    }
    gb[(size_t)row * D_ + j] = (bf16_t)((g0 + g1) + (g2 + g3));
}

// ---------------------------------------------------------------------------
// Kernel 1b: bit-pack adj (coalesced full stream, 134 MB read once).
// ---------------------------------------------------------------------------
__global__ __launch_bounds__(256) void k_pack(
    const float* __restrict__ adj, u64* __restrict__ mask)
{
    size_t widx = (size_t)blockIdx.x * 256 + threadIdx.x;
    const float4* p = (const float4*)(adj + widx * 64);
    u64 m = 0;
#pragma unroll
    for (int i = 0; i < 16; ++i) {
        float4 v = p[i];
        m |= ((u64)(v.x > 0.f)) << (i * 4 + 0);
        m |= ((u64)(v.y > 0.f)) << (i * 4 + 1);
        m |= ((u64)(v.z > 0.f)) << (i * 4 + 2);
        m |= ((u64)(v.w > 0.f)) << (i * 4 + 3);
    }
    mask[widx] = m;
}

// ---------------------------------------------------------------------------
// Kernel 2: colsum[b][m] = sum_n mask * exp(e).  Register-pipelined:
// next tile's A-frags + mask words prefetched during current tile's MFMAs.
// ---------------------------------------------------------------------------
__global__ __launch_bounds__(256) void k_colsum(
    const bf16_t* __restrict__ hb, const bf16_t* __restrict__ gb,
    const u64* __restrict__ mask, float* __restrict__ colsum)
{
    int bid = blockIdx.x;
    int b = bid >> 8;
    int rem = bid & 255;
    int mblk = rem >> 3;
    int nchunk = rem & 7;
    int wave = threadIdx.x >> 6;
    int lane = threadIdx.x & 63;
    int q = lane >> 4;
    int c = lane & 15;
    int mbase = mblk * 64 + wave * 16;
    const size_t hgoff = (size_t)b * N_ * D_;
    const u64* mb = mask + (size_t)b * N_ * 32;

    v8bf bh[4], bg[4];
#pragma unroll
    for (int kc = 0; kc < 4; ++kc) {
        size_t off = hgoff + (size_t)(mbase + c) * D_ + kc * 32 + q * 8;
        bh[kc] = *(const v8bf*)(hb + off);
        bg[kc] = *(const v8bf*)(gb + off);
    }

    int n0 = nchunk * 256;
    v8bf pag[4], pah[4];
    u64 pmw[4];
#pragma unroll
    for (int kc = 0; kc < 4; ++kc) {
        size_t off = hgoff + (size_t)(n0 + c) * D_ + kc * 32 + q * 8;
        pag[kc] = *(const v8bf*)(gb + off);
        pah[kc] = *(const v8bf*)(hb + off);
    }
#pragma unroll
    for (int r = 0; r < 4; ++r) pmw[r] = mb[(n0 + q * 4 + r) * 32 + mblk];

    float lsum = 0.f;
    for (int ns = 0; ns < 16; ++ns) {
        v8bf ag[4], ah[4];
        u64 mw[4];
#pragma unroll
        for (int kc = 0; kc < 4; ++kc) { ag[kc] = pag[kc]; ah[kc] = pah[kc]; }
#pragma unroll
        for (int r = 0; r < 4; ++r) mw[r] = pmw[r];
        if (ns < 15) {
            int nb = n0 + (ns + 1) * 16;
#pragma unroll
            for (int kc = 0; kc < 4; ++kc) {
                size_t off = hgoff + (size_t)(nb + c) * D_ + kc * 32 + q * 8;
                pag[kc] = *(const v8bf*)(gb + off);
                pah[kc] = *(const v8bf*)(hb + off);
            }
#pragma unroll
            for (int r = 0; r < 4; ++r) pmw[r] = mb[(nb + q * 4 + r) * 32 + mblk];
        }
        v4f acc = {0.f, 0.f, 0.f, 0.f};
#pragma unroll
        for (int kc = 0; kc < 4; ++kc) {
            acc = __builtin_amdgcn_mfma_f32_16x16x32_bf16(ag[kc], bh[kc], acc, 0, 0, 0);
            acc = __builtin_amdgcn_mfma_f32_16x16x32_bf16(ah[kc], bg[kc], acc, 0, 0, 0);
        }
#pragma unroll
        for (int r = 0; r < 4; ++r) {
            float ex = __expf(acc[r]);
            lsum += ((mw[r] >> (wave * 16 + c)) & 1ull) ? ex : 0.f;
        }
    }
    lsum += __shfl_xor(lsum, 16);
    lsum += __shfl_xor(lsum, 32);
    if (lane < 16) atomicAdd(&colsum[b * N_ + mbase + lane], lsum);
}

// ---------------------------------------------------------------------------
// Kernel 3: hbTs[b][d][n] = h[b][n][d] * inv(colsum[b][n]).
// Tiled 64x64 LDS transpose: coalesced read AND write; folds inv scaling.
// ---------------------------------------------------------------------------
__global__ __launch_bounds__(256) void k_scaleT(
    const bf16_t* __restrict__ hb, const float* __restrict__ colsum,
    bf16_t* __restrict__ hbTs)
{
    int bid = blockIdx.x;
    int b = bid >> 6;
    int rem = bid & 63;
    int nblk = rem >> 1;
    int dblk = rem & 1;
    int tid = threadIdx.x;
    __shared__ bf16_t sm[64][72];
    __shared__ float sinv[64];
    int n0 = nblk * 64, d0 = dblk * 64;
    int r = tid >> 3, cg = tid & 7;
#pragma unroll
    for (int rr = 0; rr < 2; ++rr) {
        int row = r + rr * 32;
        *(v8bf*)&sm[row][cg * 8] =
            *(const v8bf*)(hb + (size_t)(b * N_ + n0 + row) * D_ + d0 + cg * 8);
    }
    if (tid < 64) {
        float s = colsum[b * N_ + n0 + tid];
        sinv[tid] = (s > 0.f) ? 1.f / s : 0.f;
    }
    __syncthreads();
#pragma unroll
    for (int rr = 0; rr < 2; ++rr) {
        int dr = r + rr * 32;
        v8bf v;
#pragma unroll
        for (int jj = 0; jj < 8; ++jj)
            v[jj] = (bf16_t)((float)sm[cg * 8 + jj][dr] * sinv[cg * 8 + jj]);
        *(v8bf*)(hbTs + (size_t)(b * D_ + d0 + dr) * N_ + n0 + cg * 8) = v;
    }
}

// ---------------------------------------------------------------------------
// Kernel 4: partial h_prime = P @ Hs over an m-half.  P[n,m]=mask*exp(e).
// Chunk-granular register pipeline: t1 frags + hbTs frags + mask issued at
// chunk entry; next chunk's t0 frags issued after t0 compute.
// ---------------------------------------------------------------------------
__global__ __launch_bounds__(512, 2) void k_out(
    const bf16_t* __restrict__ hb, const bf16_t* __restrict__ gb,
    const bf16_t* __restrict__ hbTs, const u64* __restrict__ mask,
    float* __restrict__ buf0, float* __restrict__ out)
{
    int bid = blockIdx.x;
    int b = bid >> 6;
    int rem = bid & 63;
    int nblk = rem >> 1;
    int half = rem & 1;
    int tid = threadIdx.x;
    int wave = tid >> 6;
    int lane = tid & 63;
    int q = lane >> 4;
    int c = lane & 15;
    int wn = wave & 3;       // n-subtile
    int sh = wave >> 2;      // 512-col sub-half
    int nbase = nblk * 64 + wn * 16;
    const size_t hgoff = (size_t)b * N_ * D_;

    __shared__ float pbuf[8][16 * 36];
    __shared__ float hp[64][132];

    v8bf ag[4], ah[4];
#pragma unroll
    for (int kc = 0; kc < 4; ++kc) {
        size_t off = hgoff + (size_t)(nbase + c) * D_ + kc * 32 + q * 8;
        ag[kc] = *(const v8bf*)(gb + off);
        ah[kc] = *(const v8bf*)(hb + off);
    }

    v4f hpacc[8];
#pragma unroll
    for (int dt = 0; dt < 8; ++dt) hpacc[dt] = (v4f){0.f, 0.f, 0.f, 0.f};

    const u64* mb = mask + (size_t)b * N_ * 32;
    const bf16_t* hTb = hbTs + (size_t)b * D_ * N_;
    float* pw = pbuf[wave];
    int mwave = half * 1024 + sh * 512;

    auto loadEB = [&](v8bf* FH, v8bf* FG, int mt) {
#pragma unroll
        for (int kc = 0; kc < 4; ++kc) {
            size_t off = hgoff + (size_t)(mt + c) * D_ + kc * 32 + q * 8;
            FH[kc] = *(const v8bf*)(hb + off);
            FG[kc] = *(const v8bf*)(gb + off);
        }
    };

    v8bf fh0[4], fg0[4], fh1[4], fg1[4], vt[8];
    u64 mw[4];
    loadEB(fh0, fg0, mwave);                       // chunk 0, t0

    for (int ch = 0; ch < 16; ++ch) {
        int mchunk = mwave + ch * 32;
        loadEB(fh1, fg1, mchunk + 16);             // this chunk, t1
#pragma unroll
        for (int dt = 0; dt < 8; ++dt)             // hbTs frags, used at chunk end
            vt[dt] = *(const v8bf*)(hTb + (size_t)(dt * 16 + c) * N_ + mchunk + q * 8);
#pragma unroll
        for (int r = 0; r < 4; ++r)                // mask words, used mid-chunk
            mw[r] = mb[(nbase + q * 4 + r) * 32 + (mchunk >> 6)];

        int bit0 = (mchunk & 32) + c;

        // ---- E tile t0 ----
        v4f e0 = {0.f, 0.f, 0.f, 0.f};
#pragma unroll
        for (int kc = 0; kc < 4; ++kc) {
            e0 = __builtin_amdgcn_mfma_f32_16x16x32_bf16(ag[kc], fh0[kc], e0, 0, 0, 0);
            e0 = __builtin_amdgcn_mfma_f32_16x16x32_bf16(ah[kc], fg0[kc], e0, 0, 0, 0);
        }
        if (ch < 15) loadEB(fh0, fg0, mchunk + 32);  // next chunk, t0
#pragma unroll
        for (int r = 0; r < 4; ++r) {
            float ex = __expf(e0[r]);
            float pv = ((mw[r] >> bit0) & 1ull) ? ex : 0.f;
            pw[(q * 4 + r) * 36 + c] = pv;
        }

        // ---- E tile t1 ----
        v4f e1 = {0.f, 0.f, 0.f, 0.f};
#pragma unroll
        for (int kc = 0; kc < 4; ++kc) {
            e1 = __builtin_amdgcn_mfma_f32_16x16x32_bf16(ag[kc], fh1[kc], e1, 0, 0, 0);
            e1 = __builtin_amdgcn_mfma_f32_16x16x32_bf16(ah[kc], fg1[kc], e1, 0, 0, 0);
        }
#pragma unroll
        for (int r = 0; r < 4; ++r) {
            float ex = __expf(e1[r]);
            float pv = ((mw[r] >> (bit0 + 16)) & 1ull) ? ex : 0.f;
            pw[(q * 4 + r) * 36 + 16 + c] = pv;
        }

        // ---- C-layout -> A-layout transform (wave-local LDS) ----
        __builtin_amdgcn_wave_barrier();
        v4f p0 = *(const v4f*)&pw[c * 36 + q * 8];
        v4f p1 = *(const v4f*)&pw[c * 36 + q * 8 + 4];
        __builtin_amdgcn_wave_barrier();
        v8bf pf;
#pragma unroll
        for (int j2 = 0; j2 < 4; ++j2) {
            pf[j2]     = (bf16_t)p0[j2];
            pf[j2 + 4] = (bf16_t)p1[j2];
        }
#pragma unroll
        for (int dt = 0; dt < 8; ++dt)
            hpacc[dt] = __builtin_amdgcn_mfma_f32_16x16x32_bf16(pf, vt[dt], hpacc[dt], 0, 0, 0);
    }

    // combine the two sub-halves in LDS
    if (sh == 0) {
#pragma unroll
        for (int dt = 0; dt < 8; ++dt)
#pragma unroll
            for (int r = 0; r < 4; ++r)
                hp[wn * 16 + q * 4 + r][dt * 16 + c] = hpacc[dt][r];
    }
    __syncthreads();
    if (sh == 1) {
#pragma unroll
        for (int dt = 0; dt < 8; ++dt)
#pragma unroll
            for (int r = 0; r < 4; ++r)
                hp[wn * 16 + q * 4 + r][dt * 16 + c] += hpacc[dt][r];
    }
    __syncthreads();

    float* pb = (half == 0 ? buf0 : out) + ((size_t)b * N_ + nblk * 64) * D_;
    int row = tid >> 3;
    int seg = tid & 7;
#pragma unroll
    for (int i = 0; i < 4; ++i)
        *(float4*)&pb[row * D_ + seg * 16 + i * 4] =
            *(const float4*)&hp[row][seg * 16 + i * 4];
}

// ---------------------------------------------------------------------------
// Kernel 5: epilogue. hp = relu(buf0+buf1); coeff = sigmoid([x,hp]@gw + gb);
// out = coeff*x + (1-coeff)*hp.  buf1 lives in d_out (overwritten in place).
// ---------------------------------------------------------------------------
__global__ __launch_bounds__(256) void k_epi(
    const float* __restrict__ buf0, const float* __restrict__ x,
    const float* __restrict__ gw, const float* __restrict__ gbias,
    float* __restrict__ out)
{
    int row = blockIdx.x * 4 + (threadIdx.x >> 6);
    int lane = threadIdx.x & 63;
    const float* xr = x + (size_t)row * D_;
    const float* b0 = buf0 + (size_t)row * D_;
    float* orow = out + (size_t)row * D_;
    float2 xv = *(const float2*)&xr[lane * 2];
    float2 h0 = *(const float2*)&b0[lane * 2];
    float2 h1 = *(const float2*)&orow[lane * 2];
    float hp0 = fmaxf(h0.x + h1.x, 0.f);
    float hp1 = fmaxf(h0.y + h1.y, 0.f);
    float part = xv.x * gw[lane * 2] + xv.y * gw[lane * 2 + 1]
               + hp0 * gw[D_ + lane * 2] + hp1 * gw[D_ + lane * 2 + 1];
    part += __shfl_xor(part, 1);
    part += __shfl_xor(part, 2);
    part += __shfl_xor(part, 4);
    part += __shfl_xor(part, 8);
    part += __shfl_xor(part, 16);
    part += __shfl_xor(part, 32);
    float coeff = 1.f / (1.f + __expf(-(part + gbias[0])));
    float2 o;
    o.x = coeff * xv.x + (1.f - coeff) * hp0;
    o.y = coeff * xv.y + (1.f - coeff) * hp1;
    *(float2*)&orow[lane * 2] = o;
}

// ---------------------------------------------------------------------------
extern "C" void kernel_launch(void* const* d_in, const int* in_sizes, int n_in,
                              void* d_out, int out_size, void* d_ws, size_t ws_size,
                              hipStream_t stream)
{
    const float* x     = (const float*)d_in[0];
    const float* adj   = (const float*)d_in[1];
    const float* Ww    = (const float*)d_in[2];
    const float* Wb    = (const float*)d_in[3];
    const float* Aw    = (const float*)d_in[4];
    const float* gw    = (const float*)d_in[5];
    const float* gbias = (const float*)d_in[6];
    float* out = (float*)d_out;

    char* ws = (char*)d_ws;
    bf16_t* hb     = (bf16_t*)(ws);                          // 4 MB
    bf16_t* gb     = (bf16_t*)(ws + (4 << 20));              // 4 MB
    bf16_t* hbTs   = (bf16_t*)(ws + (8 << 20));              // 4 MB
    float*  colsum = (float*)(ws + (12 << 20));              // 64 KB
    u64*    mask   = (u64*)(ws + (13 << 20));                // 4 MB
    float*  buf0   = (float*)(ws + (17 << 20));              // 8 MB

    hipMemsetAsync(colsum, 0, B_ * N_ * sizeof(float), stream);
    k_hg<<<B_ * N_, 128, 0, stream>>>(x, Ww, Wb, Aw, hb, gb);
    k_pack<<<B_ * N_ * 32 / 256, 256, 0, stream>>>(adj, mask);
    k_colsum<<<2048, 256, 0, stream>>>(hb, gb, mask, colsum);
    k_scaleT<<<512, 256, 0, stream>>>(hb, colsum, hbTs);
    k_out<<<512, 512, 0, stream>>>(hb, gb, hbTs, mask, buf0, out);
    k_epi<<<B_ * N_ / 4, 256, 0, stream>>>(buf0, x, gw, gbias, out);
}

// Round 4
// 434.214 us; speedup vs baseline: 1.4525x; 1.4015x over previous
//
#include <hip/hip_runtime.h>
#include <hip/hip_bf16.h>

#define B_ 8
#define N_ 2048
#define D_ 128

typedef __bf16 bf16_t;
typedef __bf16 v8bf __attribute__((ext_vector_type(8)));
typedef float  v4f  __attribute__((ext_vector_type(4)));
typedef unsigned long long u64;

// ---------------------------------------------------------------------------
// k_prep: WT[o][i] = (bf16)Ww[i][o]; AT[o][i] = (bf16)Aw[i][o].
// ---------------------------------------------------------------------------
__global__ __launch_bounds__(256) void k_prep(
    const float* __restrict__ Ww, const float* __restrict__ Aw,
    bf16_t* __restrict__ WT, bf16_t* __restrict__ AT)
{
    int idx = blockIdx.x * 256 + threadIdx.x;   // 0..16383
    int o = idx >> 7, i = idx & 127;
    WT[idx] = (bf16_t)Ww[i * D_ + o];
    AT[idx] = (bf16_t)Aw[i * D_ + o];
}

// ---------------------------------------------------------------------------
// k_hg (MFMA): h = x@W + b; g = h@A.  Block = 64 rows, 4 waves x 16 rows.
// A-frags from x (fp32->bf16), B-frags from WT/AT (bf16, L2-hot).
// h round-trips a per-wave LDS tile for (a) bf16 A-frags of the g-GEMM and
// (b) coalesced row-major stores.
// ---------------------------------------------------------------------------
__global__ __launch_bounds__(256) void k_hg(
    const float* __restrict__ x, const float* __restrict__ Wb,
    const bf16_t* __restrict__ WT, const bf16_t* __restrict__ AT,
    bf16_t* __restrict__ hb, bf16_t* __restrict__ gb)
{
    int wave = threadIdx.x >> 6;
    int lane = threadIdx.x & 63;
    int q = lane >> 4;
    int c = lane & 15;
    int nrow0 = blockIdx.x * 64 + wave * 16;    // global flat row (b*N+n)

    __shared__ float pw_all[4][16][132];
    float (*pw)[132] = pw_all[wave];

    // A-frags from x
    v8bf ax[4];
#pragma unroll
    for (int kc = 0; kc < 4; ++kc) {
        const float* src = x + (size_t)(nrow0 + c) * D_ + kc * 32 + q * 8;
        float4 f0 = *(const float4*)src;
        float4 f1 = *(const float4*)(src + 4);
        v8bf a;
        a[0]=(bf16_t)f0.x; a[1]=(bf16_t)f0.y; a[2]=(bf16_t)f0.z; a[3]=(bf16_t)f0.w;
        a[4]=(bf16_t)f1.x; a[5]=(bf16_t)f1.y; a[6]=(bf16_t)f1.z; a[7]=(bf16_t)f1.w;
        ax[kc] = a;
    }

    // h-GEMM: 8 d-tiles
#pragma unroll
    for (int ct = 0; ct < 8; ++ct) {
        float bias = Wb[ct * 16 + c];
        v4f acc = {bias, bias, bias, bias};
#pragma unroll
        for (int kc = 0; kc < 4; ++kc) {
            v8bf bw = *(const v8bf*)(WT + (size_t)(ct * 16 + c) * D_ + kc * 32 + q * 8);
            acc = __builtin_amdgcn_mfma_f32_16x16x32_bf16(ax[kc], bw, acc, 0, 0, 0);
        }
#pragma unroll
        for (int r = 0; r < 4; ++r) pw[q * 4 + r][ct * 16 + c] = acc[r];
    }
    __builtin_amdgcn_wave_barrier();

    // bf16 A-frags for g-GEMM from LDS
    v8bf ahf[4];
#pragma unroll
    for (int kc = 0; kc < 4; ++kc) {
        v4f p0 = *(const v4f*)&pw[c][kc * 32 + q * 8];
        v4f p1 = *(const v4f*)&pw[c][kc * 32 + q * 8 + 4];
        v8bf a;
#pragma unroll
        for (int j = 0; j < 4; ++j) { a[j] = (bf16_t)p0[j]; a[j+4] = (bf16_t)p1[j]; }
        ahf[kc] = a;
    }
    // coalesced h store
    {
        int row = lane >> 2, seg = lane & 3;
#pragma unroll
        for (int v = 0; v < 4; ++v) {
            v8bf hv;
#pragma unroll
            for (int j = 0; j < 8; ++j) hv[j] = (bf16_t)pw[row][seg * 32 + v * 8 + j];
            *(v8bf*)(hb + (size_t)(nrow0 + row) * D_ + seg * 32 + v * 8) = hv;
        }
    }
    __builtin_amdgcn_wave_barrier();

    // g-GEMM
#pragma unroll
    for (int ct = 0; ct < 8; ++ct) {
        v4f acc = {0.f, 0.f, 0.f, 0.f};
#pragma unroll
        for (int kc = 0; kc < 4; ++kc) {
            v8bf bw = *(const v8bf*)(AT + (size_t)(ct * 16 + c) * D_ + kc * 32 + q * 8);
            acc = __builtin_amdgcn_mfma_f32_16x16x32_bf16(ahf[kc], bw, acc, 0, 0, 0);
        }
#pragma unroll
        for (int r = 0; r < 4; ++r) pw[q * 4 + r][ct * 16 + c] = acc[r];
    }
    __builtin_amdgcn_wave_barrier();
    {
        int row = lane >> 2, seg = lane & 3;
#pragma unroll
        for (int v = 0; v < 4; ++v) {
            v8bf gv;
#pragma unroll
            for (int j = 0; j < 8; ++j) gv[j] = (bf16_t)pw[row][seg * 32 + v * 8 + j];
            *(v8bf*)(gb + (size_t)(nrow0 + row) * D_ + seg * 32 + v * 8) = gv;
        }
    }
}

// ---------------------------------------------------------------------------
// k_pack: bit-pack adj (134 MB coalesced read -> 4 MB mask).
// ---------------------------------------------------------------------------
__global__ __launch_bounds__(256) void k_pack(
    const float* __restrict__ adj, u64* __restrict__ mask)
{
    size_t widx = (size_t)blockIdx.x * 256 + threadIdx.x;
    const float4* p = (const float4*)(adj + widx * 64);
    u64 m = 0;
#pragma unroll
    for (int i = 0; i < 16; ++i) {
        float4 v = p[i];
        m |= ((u64)(v.x > 0.f)) << (i * 4 + 0);
        m |= ((u64)(v.y > 0.f)) << (i * 4 + 1);
        m |= ((u64)(v.z > 0.f)) << (i * 4 + 2);
        m |= ((u64)(v.w > 0.f)) << (i * 4 + 3);
    }
    mask[widx] = m;
}

// ---------------------------------------------------------------------------
// k_att: computes E tiles, P~ = mask*exp(e) -> bf16 Pt[b][n][m], and
// colsum[b][m] (atomic).  b = bid&7 for XCD-L2 locality.
// grid 2048: b(8) x nblk(32, 64 n-rows) x mgrp(8, 256 m-cols); 4 waves.
// ---------------------------------------------------------------------------
__global__ __launch_bounds__(256) void k_att(
    const bf16_t* __restrict__ hb, const bf16_t* __restrict__ gb,
    const u64* __restrict__ mask, float* __restrict__ colsum,
    bf16_t* __restrict__ Pt)
{
    int bid = blockIdx.x;
    int b = bid & 7;
    int rest = bid >> 3;          // 0..255
    int nblk = rest >> 3;         // 0..31
    int mgrp = rest & 7;          // 0..7
    int wave = threadIdx.x >> 6;
    int lane = threadIdx.x & 63;
    int q = lane >> 4;
    int c = lane & 15;
    int nbase = nblk * 64 + wave * 16;
    const size_t hgoff = (size_t)b * N_ * D_;
    const u64* mb = mask + (size_t)b * N_ * 32;

    __shared__ float eb_all[4][16][68];
    float (*eb)[68] = eb_all[wave];

    v8bf ag[4], ah[4];
#pragma unroll
    for (int kc = 0; kc < 4; ++kc) {
        size_t off = hgoff + (size_t)(nbase + c) * D_ + kc * 32 + q * 8;
        ag[kc] = *(const v8bf*)(gb + off);
        ah[kc] = *(const v8bf*)(hb + off);
    }

    int m0 = mgrp * 256;
    for (int grp = 0; grp < 4; ++grp) {
        int mg = m0 + grp * 64;
        u64 mw[4];
#pragma unroll
        for (int r = 0; r < 4; ++r) mw[r] = mb[(nbase + q * 4 + r) * 32 + (mg >> 6)];
#pragma unroll
        for (int t = 0; t < 4; ++t) {
            int mt = mg + t * 16;
            v4f e = {0.f, 0.f, 0.f, 0.f};
#pragma unroll
            for (int kc = 0; kc < 4; ++kc) {
                size_t off = hgoff + (size_t)(mt + c) * D_ + kc * 32 + q * 8;
                v8bf bh = *(const v8bf*)(hb + off);
                v8bf bg = *(const v8bf*)(gb + off);
                e = __builtin_amdgcn_mfma_f32_16x16x32_bf16(ag[kc], bh, e, 0, 0, 0);
                e = __builtin_amdgcn_mfma_f32_16x16x32_bf16(ah[kc], bg, e, 0, 0, 0);
            }
            float cs = 0.f;
#pragma unroll
            for (int r = 0; r < 4; ++r) {
                float ex = __expf(e[r]);
                float pv = ((mw[r] >> (t * 16 + c)) & 1ull) ? ex : 0.f;
                eb[q * 4 + r][t * 16 + c] = pv;
                cs += pv;
            }
            cs += __shfl_xor(cs, 16);
            cs += __shfl_xor(cs, 32);
            if (lane < 16) atomicAdd(&colsum[b * N_ + mt + lane], cs);
        }
        __builtin_amdgcn_wave_barrier();
        // coalesced bf16 write of this 16n x 64m slab
        int row = lane >> 2, seg = lane & 3;
        v8bf o0, o1;
#pragma unroll
        for (int j = 0; j < 8; ++j) {
            o0[j] = (bf16_t)eb[row][seg * 16 + j];
            o1[j] = (bf16_t)eb[row][seg * 16 + 8 + j];
        }
        bf16_t* dst = Pt + ((size_t)b * N_ + nbase + row) * N_ + mg + seg * 16;
        *(v8bf*)dst = o0;
        *(v8bf*)(dst + 8) = o1;
        __builtin_amdgcn_wave_barrier();
    }
}

// ---------------------------------------------------------------------------
// k_scaleT: hbTs[b][d][m] = h[b][m][d] * inv(colsum[b][m]).
// ---------------------------------------------------------------------------
__global__ __launch_bounds__(256) void k_scaleT(
    const bf16_t* __restrict__ hb, const float* __restrict__ colsum,
    bf16_t* __restrict__ hbTs)
{
    int bid = blockIdx.x;
    int b = bid >> 6;
    int rem = bid & 63;
    int nblk = rem >> 1;
    int dblk = rem & 1;
    int tid = threadIdx.x;
    __shared__ bf16_t sm[64][72];
    __shared__ float sinv[64];
    int n0 = nblk * 64, d0 = dblk * 64;
    int r = tid >> 3, cg = tid & 7;
#pragma unroll
    for (int rr = 0; rr < 2; ++rr) {
        int row = r + rr * 32;
        *(v8bf*)&sm[row][cg * 8] =
            *(const v8bf*)(hb + (size_t)(b * N_ + n0 + row) * D_ + d0 + cg * 8);
    }
    if (tid < 64) {
        float s = colsum[b * N_ + n0 + tid];
        sinv[tid] = (s > 0.f) ? 1.f / s : 0.f;
    }
    __syncthreads();
#pragma unroll
    for (int rr = 0; rr < 2; ++rr) {
        int dr = r + rr * 32;
        v8bf v;
#pragma unroll
        for (int jj = 0; jj < 8; ++jj)
            v[jj] = (bf16_t)((float)sm[cg * 8 + jj][dr] * sinv[cg * 8 + jj]);
        *(v8bf*)(hbTs + (size_t)(b * D_ + d0 + dr) * N_ + n0 + cg * 8) = v;
    }
}

// ---------------------------------------------------------------------------
// k_out: h_prime = Pt @ hbTs (pure GEMM), fused relu+gate+output epilogue.
// grid 256 (b = bid&7), 1024 thr = 16 waves: wn(4 n-subtiles) x sh(4 m-quarters).
// ---------------------------------------------------------------------------
__global__ __launch_bounds__(1024) void k_out(
    const bf16_t* __restrict__ Pt, const bf16_t* __restrict__ hbTs,
    const float* __restrict__ x, const float* __restrict__ gw,
    const float* __restrict__ gbias, float* __restrict__ out)
{
    int bid = blockIdx.x;
    int b = bid & 7;
    int nblk = bid >> 3;          // 0..31
    int tid = threadIdx.x;
    int wave = tid >> 6;
    int lane = tid & 63;
    int q = lane >> 4;
    int c = lane & 15;
    int wn = wave & 3;
    int sh = wave >> 2;           // m-quarter
    int nbase = nblk * 64 + wn * 16;
    int msh = sh * 512;

    __shared__ float hp[64][132];

    const bf16_t* Pr = Pt + ((size_t)b * N_ + nbase + c) * N_;
    const bf16_t* hTb = hbTs + (size_t)b * D_ * N_;

    v4f acc[8];
#pragma unroll
    for (int dt = 0; dt < 8; ++dt) acc[dt] = (v4f){0.f, 0.f, 0.f, 0.f};

    v8bf af, vt[8], afn, vtn[8];
    af = *(const v8bf*)(Pr + msh + q * 8);
#pragma unroll
    for (int dt = 0; dt < 8; ++dt)
        vt[dt] = *(const v8bf*)(hTb + (size_t)(dt * 16 + c) * N_ + msh + q * 8);

    for (int ch = 0; ch < 16; ++ch) {
        int mch = msh + ch * 32;
        if (ch < 15) {
            afn = *(const v8bf*)(Pr + mch + 32 + q * 8);
#pragma unroll
            for (int dt = 0; dt < 8; ++dt)
                vtn[dt] = *(const v8bf*)(hTb + (size_t)(dt * 16 + c) * N_ + mch + 32 + q * 8);
        }
#pragma unroll
        for (int dt = 0; dt < 8; ++dt)
            acc[dt] = __builtin_amdgcn_mfma_f32_16x16x32_bf16(af, vt[dt], acc[dt], 0, 0, 0);
        af = afn;
#pragma unroll
        for (int dt = 0; dt < 8; ++dt) vt[dt] = vtn[dt];
    }

    // combine the 4 m-quarters
    if (sh == 0) {
#pragma unroll
        for (int dt = 0; dt < 8; ++dt)
#pragma unroll
            for (int r = 0; r < 4; ++r)
                hp[wn * 16 + q * 4 + r][dt * 16 + c] = acc[dt][r];
    }
    __syncthreads();
#pragma unroll
    for (int s = 1; s < 4; ++s) {
        if (sh == s) {
#pragma unroll
            for (int dt = 0; dt < 8; ++dt)
#pragma unroll
                for (int r = 0; r < 4; ++r)
                    hp[wn * 16 + q * 4 + r][dt * 16 + c] += acc[dt][r];
        }
        __syncthreads();
    }

    // fused epilogue: 1024 thr = 64 rows x 16 segs x 8 d
    int row = tid >> 4;
    int seg = tid & 15;
    size_t g = (size_t)b * N_ + nblk * 64 + row;
    const float* xr = x + g * D_ + seg * 8;
    float4 xa = *(const float4*)xr;
    float4 xb = *(const float4*)(xr + 4);
    float hv[8];
#pragma unroll
    for (int j = 0; j < 8; ++j) hv[j] = fmaxf(hp[row][seg * 8 + j], 0.f);
    float part = xa.x * gw[seg*8+0] + xa.y * gw[seg*8+1] + xa.z * gw[seg*8+2] + xa.w * gw[seg*8+3]
               + xb.x * gw[seg*8+4] + xb.y * gw[seg*8+5] + xb.z * gw[seg*8+6] + xb.w * gw[seg*8+7];
#pragma unroll
    for (int j = 0; j < 8; ++j) part += hv[j] * gw[D_ + seg * 8 + j];
    part += __shfl_xor(part, 1);
    part += __shfl_xor(part, 2);
    part += __shfl_xor(part, 4);
    part += __shfl_xor(part, 8);
    float coeff = 1.f / (1.f + __expf(-(part + gbias[0])));
    float4 o0, o1;
    o0.x = coeff * xa.x + (1.f - coeff) * hv[0];
    o0.y = coeff * xa.y + (1.f - coeff) * hv[1];
    o0.z = coeff * xa.z + (1.f - coeff) * hv[2];
    o0.w = coeff * xa.w + (1.f - coeff) * hv[3];
    o1.x = coeff * xb.x + (1.f - coeff) * hv[4];
    o1.y = coeff * xb.y + (1.f - coeff) * hv[5];
    o1.z = coeff * xb.z + (1.f - coeff) * hv[6];
    o1.w = coeff * xb.w + (1.f - coeff) * hv[7];
    float* orow = out + g * D_ + seg * 8;
    *(float4*)orow = o0;
    *(float4*)(orow + 4) = o1;
}

// ---------------------------------------------------------------------------
extern "C" void kernel_launch(void* const* d_in, const int* in_sizes, int n_in,
                              void* d_out, int out_size, void* d_ws, size_t ws_size,
                              hipStream_t stream)
{
    const float* x     = (const float*)d_in[0];
    const float* adj   = (const float*)d_in[1];
    const float* Ww    = (const float*)d_in[2];
    const float* Wb    = (const float*)d_in[3];
    const float* Aw    = (const float*)d_in[4];
    const float* gw    = (const float*)d_in[5];
    const float* gbias = (const float*)d_in[6];
    float* out = (float*)d_out;

    char* ws = (char*)d_ws;
    bf16_t* hb     = (bf16_t*)(ws);                          // 4 MB
    bf16_t* gb     = (bf16_t*)(ws + (4 << 20));              // 4 MB
    bf16_t* hbTs   = (bf16_t*)(ws + (8 << 20));              // 4 MB
    float*  colsum = (float*)(ws + (12 << 20));              // 64 KB
    u64*    mask   = (u64*)(ws + (13 << 20));                // 4 MB
    bf16_t* Pt     = (bf16_t*)(ws + (17 << 20));             // 64 MB
    bf16_t* WT     = (bf16_t*)(ws + (81 << 20));             // 32 KB
    bf16_t* AT     = (bf16_t*)(ws + (81 << 20) + (32 << 10));// 32 KB

    hipMemsetAsync(colsum, 0, B_ * N_ * sizeof(float), stream);
    k_prep<<<64, 256, 0, stream>>>(Ww, Aw, WT, AT);
    k_hg<<<B_ * N_ / 64, 256, 0, stream>>>(x, Wb, WT, AT, hb, gb);
    k_pack<<<B_ * N_ * 32 / 256, 256, 0, stream>>>(adj, mask);
    k_att<<<2048, 256, 0, stream>>>(hb, gb, mask, colsum, Pt);
    k_scaleT<<<512, 256, 0, stream>>>(hb, colsum, hbTs);
    k_out<<<256, 1024, 0, stream>>>(Pt, hbTs, x, gw, gbias, out);
}

// Round 5
// 316.918 us; speedup vs baseline: 1.9901x; 1.3701x over previous
//
#include <hip/hip_runtime.h>
#include <hip/hip_bf16.h>

#define B_ 8
#define N_ 2048
#define D_ 128

typedef __bf16 bf16_t;
typedef __bf16 v8bf __attribute__((ext_vector_type(8)));
typedef float  v4f  __attribute__((ext_vector_type(4)));

// ---------------------------------------------------------------------------
// k_prep: WT[o][i] = (bf16)Ww[i][o]; AT[o][i] = (bf16)Aw[i][o].
// ---------------------------------------------------------------------------
__global__ __launch_bounds__(256) void k_prep(
    const float* __restrict__ Ww, const float* __restrict__ Aw,
    bf16_t* __restrict__ WT, bf16_t* __restrict__ AT)
{
    int idx = blockIdx.x * 256 + threadIdx.x;   // 0..16383
    int o = idx >> 7, i = idx & 127;
    WT[idx] = (bf16_t)Ww[i * D_ + o];
    AT[idx] = (bf16_t)Aw[i * D_ + o];
}

// ---------------------------------------------------------------------------
// k_hg (MFMA): h = x@W + b; g = h@A.  Block = 64 rows, 4 waves x 16 rows.
// ---------------------------------------------------------------------------
__global__ __launch_bounds__(256) void k_hg(
    const float* __restrict__ x, const float* __restrict__ Wb,
    const bf16_t* __restrict__ WT, const bf16_t* __restrict__ AT,
    bf16_t* __restrict__ hb, bf16_t* __restrict__ gb)
{
    int wave = threadIdx.x >> 6;
    int lane = threadIdx.x & 63;
    int q = lane >> 4;
    int c = lane & 15;
    int nrow0 = blockIdx.x * 64 + wave * 16;    // global flat row (b*N+n)

    __shared__ float pw_all[4][16][132];
    float (*pw)[132] = pw_all[wave];

    v8bf ax[4];
#pragma unroll
    for (int kc = 0; kc < 4; ++kc) {
        const float* src = x + (size_t)(nrow0 + c) * D_ + kc * 32 + q * 8;
        float4 f0 = *(const float4*)src;
        float4 f1 = *(const float4*)(src + 4);
        v8bf a;
        a[0]=(bf16_t)f0.x; a[1]=(bf16_t)f0.y; a[2]=(bf16_t)f0.z; a[3]=(bf16_t)f0.w;
        a[4]=(bf16_t)f1.x; a[5]=(bf16_t)f1.y; a[6]=(bf16_t)f1.z; a[7]=(bf16_t)f1.w;
        ax[kc] = a;
    }

#pragma unroll
    for (int ct = 0; ct < 8; ++ct) {
        float bias = Wb[ct * 16 + c];
        v4f acc = {bias, bias, bias, bias};
#pragma unroll
        for (int kc = 0; kc < 4; ++kc) {
            v8bf bw = *(const v8bf*)(WT + (size_t)(ct * 16 + c) * D_ + kc * 32 + q * 8);
            acc = __builtin_amdgcn_mfma_f32_16x16x32_bf16(ax[kc], bw, acc, 0, 0, 0);
        }
#pragma unroll
        for (int r = 0; r < 4; ++r) pw[q * 4 + r][ct * 16 + c] = acc[r];
    }
    __builtin_amdgcn_wave_barrier();

    v8bf ahf[4];
#pragma unroll
    for (int kc = 0; kc < 4; ++kc) {
        v4f p0 = *(const v4f*)&pw[c][kc * 32 + q * 8];
        v4f p1 = *(const v4f*)&pw[c][kc * 32 + q * 8 + 4];
        v8bf a;
#pragma unroll
        for (int j = 0; j < 4; ++j) { a[j] = (bf16_t)p0[j]; a[j+4] = (bf16_t)p1[j]; }
        ahf[kc] = a;
    }
    {
        int row = lane >> 2, seg = lane & 3;
#pragma unroll
        for (int v = 0; v < 4; ++v) {
            v8bf hv;
#pragma unroll
            for (int j = 0; j < 8; ++j) hv[j] = (bf16_t)pw[row][seg * 32 + v * 8 + j];
            *(v8bf*)(hb + (size_t)(nrow0 + row) * D_ + seg * 32 + v * 8) = hv;
        }
    }
    __builtin_amdgcn_wave_barrier();

#pragma unroll
    for (int ct = 0; ct < 8; ++ct) {
        v4f acc = {0.f, 0.f, 0.f, 0.f};
#pragma unroll
        for (int kc = 0; kc < 4; ++kc) {
            v8bf bw = *(const v8bf*)(AT + (size_t)(ct * 16 + c) * D_ + kc * 32 + q * 8);
            acc = __builtin_amdgcn_mfma_f32_16x16x32_bf16(ahf[kc], bw, acc, 0, 0, 0);
        }
#pragma unroll
        for (int r = 0; r < 4; ++r) pw[q * 4 + r][ct * 16 + c] = acc[r];
    }
    __builtin_amdgcn_wave_barrier();
    {
        int row = lane >> 2, seg = lane & 3;
#pragma unroll
        for (int v = 0; v < 4; ++v) {
            v8bf gv;
#pragma unroll
            for (int j = 0; j < 8; ++j) gv[j] = (bf16_t)pw[row][seg * 32 + v * 8 + j];
            *(v8bf*)(gb + (size_t)(nrow0 + row) * D_ + seg * 32 + v * 8) = gv;
        }
    }
}

// ---------------------------------------------------------------------------
// k_att: E tiles -> P~ = (adj>0)*exp(e) -> bf16 Pt + colsum (atomic).
// grid 2048: b(8, =bid&7 for XCD-L2) x nblk(32) x mgrp(8).  4 waves.
// Each wave: ALL 64 n-rows (4 subtile A-frags in regs) x private 64-m span.
// Per 16-m tile: 8 B-loads + 16 adj loads -> 32 MFMAs (4 indep chains).
// adj read directly here (line-aligned: 16 lanes consume each 64B line).
// ---------------------------------------------------------------------------
__global__ __launch_bounds__(256, 2) void k_att(
    const bf16_t* __restrict__ hb, const bf16_t* __restrict__ gb,
    const float* __restrict__ adj, float* __restrict__ colsum,
    bf16_t* __restrict__ Pt)
{
    int bid = blockIdx.x;
    int b = bid & 7;
    int rest = bid >> 3;          // 0..255
    int nblk = rest >> 3;         // 0..31
    int mgrp = rest & 7;          // 0..7
    int wave = threadIdx.x >> 6;
    int lane = threadIdx.x & 63;
    int q = lane >> 4;
    int c = lane & 15;
    int nbase = nblk * 64;
    int mwav = mgrp * 256 + wave * 64;
    const size_t hgoff = (size_t)b * N_ * D_;
    const float* adjb = adj + (size_t)b * N_ * N_;

    __shared__ float eb_all[4][64][68];
    float (*eb)[68] = eb_all[wave];

    // A-frags: 4 n-subtiles (persistent, 128 VGPRs)
    v8bf ag[4][4], ah[4][4];
#pragma unroll
    for (int sub = 0; sub < 4; ++sub)
#pragma unroll
        for (int kc = 0; kc < 4; ++kc) {
            size_t off = hgoff + (size_t)(nbase + sub * 16 + c) * D_ + kc * 32 + q * 8;
            ag[sub][kc] = *(const v8bf*)(gb + off);
            ah[sub][kc] = *(const v8bf*)(hb + off);
        }

    for (int t = 0; t < 4; ++t) {
        int mt = mwav + t * 16;
        // adj values: issue early, 16 independent 4B loads
        float av[4][4];
#pragma unroll
        for (int sub = 0; sub < 4; ++sub)
#pragma unroll
            for (int r = 0; r < 4; ++r)
                av[sub][r] = adjb[(size_t)(nbase + sub * 16 + q * 4 + r) * N_ + mt + c];
        // B-frags: 8 independent 16B loads
        v8bf bh[4], bg[4];
#pragma unroll
        for (int kc = 0; kc < 4; ++kc) {
            size_t off = hgoff + (size_t)(mt + c) * D_ + kc * 32 + q * 8;
            bh[kc] = *(const v8bf*)(hb + off);
            bg[kc] = *(const v8bf*)(gb + off);
        }
        v4f e[4];
#pragma unroll
        for (int sub = 0; sub < 4; ++sub) e[sub] = (v4f){0.f, 0.f, 0.f, 0.f};
#pragma unroll
        for (int kc = 0; kc < 4; ++kc)
#pragma unroll
            for (int sub = 0; sub < 4; ++sub) {
                e[sub] = __builtin_amdgcn_mfma_f32_16x16x32_bf16(ag[sub][kc], bh[kc], e[sub], 0, 0, 0);
                e[sub] = __builtin_amdgcn_mfma_f32_16x16x32_bf16(ah[sub][kc], bg[kc], e[sub], 0, 0, 0);
            }
        float cs = 0.f;
#pragma unroll
        for (int sub = 0; sub < 4; ++sub)
#pragma unroll
            for (int r = 0; r < 4; ++r) {
                float ex = __expf(e[sub][r]);
                float pv = (av[sub][r] > 0.f) ? ex : 0.f;
                eb[sub * 16 + q * 4 + r][t * 16 + c] = pv;
                cs += pv;
            }
        cs += __shfl_xor(cs, 16);
        cs += __shfl_xor(cs, 32);
        if (lane < 16) atomicAdd(&colsum[b * N_ + mt + lane], cs);
    }
    __builtin_amdgcn_wave_barrier();
    // pack 64n x 64m to bf16, coalesced 16B stores
    int prow = lane >> 3, pseg = lane & 7;
#pragma unroll
    for (int pass = 0; pass < 8; ++pass) {
        int row = pass * 8 + prow;
        v4f p0 = *(const v4f*)&eb[row][pseg * 8];
        v4f p1 = *(const v4f*)&eb[row][pseg * 8 + 4];
        v8bf o;
#pragma unroll
        for (int j = 0; j < 4; ++j) { o[j] = (bf16_t)p0[j]; o[j + 4] = (bf16_t)p1[j]; }
        *(v8bf*)(Pt + ((size_t)b * N_ + nbase + row) * N_ + mwav + pseg * 8) = o;
    }
}

// ---------------------------------------------------------------------------
// k_scaleT: hbTs[b][d][m] = h[b][m][d] * inv(colsum[b][m]).
// ---------------------------------------------------------------------------
__global__ __launch_bounds__(256) void k_scaleT(
    const bf16_t* __restrict__ hb, const float* __restrict__ colsum,
    bf16_t* __restrict__ hbTs)
{
    int bid = blockIdx.x;
    int b = bid >> 6;
    int rem = bid & 63;
    int nblk = rem >> 1;
    int dblk = rem & 1;
    int tid = threadIdx.x;
    __shared__ bf16_t sm[64][72];
    __shared__ float sinv[64];
    int n0 = nblk * 64, d0 = dblk * 64;
    int r = tid >> 3, cg = tid & 7;
#pragma unroll
    for (int rr = 0; rr < 2; ++rr) {
        int row = r + rr * 32;
        *(v8bf*)&sm[row][cg * 8] =
            *(const v8bf*)(hb + (size_t)(b * N_ + n0 + row) * D_ + d0 + cg * 8);
    }
    if (tid < 64) {
        float s = colsum[b * N_ + n0 + tid];
        sinv[tid] = (s > 0.f) ? 1.f / s : 0.f;
    }
    __syncthreads();
#pragma unroll
    for (int rr = 0; rr < 2; ++rr) {
        int dr = r + rr * 32;
        v8bf v;
#pragma unroll
        for (int jj = 0; jj < 8; ++jj)
            v[jj] = (bf16_t)((float)sm[cg * 8 + jj][dr] * sinv[cg * 8 + jj]);
        *(v8bf*)(hbTs + (size_t)(b * D_ + d0 + dr) * N_ + n0 + cg * 8) = v;
    }
}

// ---------------------------------------------------------------------------
// k_out: h_prime = Pt @ hbTs, fused relu+gate+output epilogue.
// grid 256 (b=bid&7), 512 thr = 8 waves; wave w owns m-octant [w*256,+256),
// covering ALL 64 n x 128 d (acc = 4 sub x 8 dt = 128 AGPRs).
// Per 32-m chunk: 4 A + 8 B loads -> 32 MFMAs.
// ---------------------------------------------------------------------------
__global__ __launch_bounds__(512, 2) void k_out(
    const bf16_t* __restrict__ Pt, const bf16_t* __restrict__ hbTs,
    const float* __restrict__ x, const float* __restrict__ gw,
    const float* __restrict__ gbias, float* __restrict__ out)
{
    int bid = blockIdx.x;
    int b = bid & 7;
    int nblk = bid >> 3;          // 0..31
    int tid = threadIdx.x;
    int wave = tid >> 6;          // m-octant
    int lane = tid & 63;
    int q = lane >> 4;
    int c = lane & 15;
    int nbase = nblk * 64;
    int m0 = wave * 256;

    __shared__ float hp[64][132];

    const bf16_t* hTb = hbTs + (size_t)b * D_ * N_;
    const bf16_t* Pb  = Pt + (size_t)b * N_ * N_;

    v4f acc[4][8];
#pragma unroll
    for (int sub = 0; sub < 4; ++sub)
#pragma unroll
        for (int dt = 0; dt < 8; ++dt) acc[sub][dt] = (v4f){0.f, 0.f, 0.f, 0.f};

    for (int ch = 0; ch < 8; ++ch) {
        int mch = m0 + ch * 32;
        v8bf a[4];
#pragma unroll
        for (int sub = 0; sub < 4; ++sub)
            a[sub] = *(const v8bf*)(Pb + (size_t)(nbase + sub * 16 + c) * N_ + mch + q * 8);
        v8bf vt[8];
#pragma unroll
        for (int dt = 0; dt < 8; ++dt)
            vt[dt] = *(const v8bf*)(hTb + (size_t)(dt * 16 + c) * N_ + mch + q * 8);
#pragma unroll
        for (int dt = 0; dt < 8; ++dt)
#pragma unroll
            for (int sub = 0; sub < 4; ++sub)
                acc[sub][dt] = __builtin_amdgcn_mfma_f32_16x16x32_bf16(a[sub], vt[dt], acc[sub][dt], 0, 0, 0);
    }

    // combine the 8 m-octants in LDS
    if (wave == 0) {
#pragma unroll
        for (int sub = 0; sub < 4; ++sub)
#pragma unroll
            for (int dt = 0; dt < 8; ++dt)
#pragma unroll
                for (int r = 0; r < 4; ++r)
                    hp[sub * 16 + q * 4 + r][dt * 16 + c] = acc[sub][dt][r];
    }
    __syncthreads();
#pragma unroll
    for (int wv = 1; wv < 8; ++wv) {
        if (wave == wv) {
#pragma unroll
            for (int sub = 0; sub < 4; ++sub)
#pragma unroll
                for (int dt = 0; dt < 8; ++dt)
#pragma unroll
                    for (int r = 0; r < 4; ++r)
                        hp[sub * 16 + q * 4 + r][dt * 16 + c] += acc[sub][dt][r];
        }
        __syncthreads();
    }

    // fused epilogue: 512 thr = 64 rows x 8 segs x 16 d
    int row = tid >> 3;
    int seg = tid & 7;
    size_t g = (size_t)b * N_ + nbase + row;
    const float* xr = x + g * D_ + seg * 16;
    float xv[16], hv[16];
#pragma unroll
    for (int j = 0; j < 16; j += 4) {
        float4 f = *(const float4*)(xr + j);
        xv[j] = f.x; xv[j+1] = f.y; xv[j+2] = f.z; xv[j+3] = f.w;
    }
#pragma unroll
    for (int j = 0; j < 16; ++j) hv[j] = fmaxf(hp[row][seg * 16 + j], 0.f);
    float part = 0.f;
#pragma unroll
    for (int j = 0; j < 16; ++j)
        part += xv[j] * gw[seg * 16 + j] + hv[j] * gw[D_ + seg * 16 + j];
    part += __shfl_xor(part, 1);
    part += __shfl_xor(part, 2);
    part += __shfl_xor(part, 4);
    float coeff = 1.f / (1.f + __expf(-(part + gbias[0])));
    float* orow = out + g * D_ + seg * 16;
#pragma unroll
    for (int j = 0; j < 16; j += 4) {
        float4 o;
        o.x = coeff * xv[j]   + (1.f - coeff) * hv[j];
        o.y = coeff * xv[j+1] + (1.f - coeff) * hv[j+1];
        o.z = coeff * xv[j+2] + (1.f - coeff) * hv[j+2];
        o.w = coeff * xv[j+3] + (1.f - coeff) * hv[j+3];
        *(float4*)(orow + j) = o;
    }
}

// ---------------------------------------------------------------------------
extern "C" void kernel_launch(void* const* d_in, const int* in_sizes, int n_in,
                              void* d_out, int out_size, void* d_ws, size_t ws_size,
                              hipStream_t stream)
{
    const float* x     = (const float*)d_in[0];
    const float* adj   = (const float*)d_in[1];
    const float* Ww    = (const float*)d_in[2];
    const float* Wb    = (const float*)d_in[3];
    const float* Aw    = (const float*)d_in[4];
    const float* gw    = (const float*)d_in[5];
    const float* gbias = (const float*)d_in[6];
    float* out = (float*)d_out;

    char* ws = (char*)d_ws;
    bf16_t* hb     = (bf16_t*)(ws);                          // 4 MB
    bf16_t* gb     = (bf16_t*)(ws + (4 << 20));              // 4 MB
    bf16_t* hbTs   = (bf16_t*)(ws + (8 << 20));              // 4 MB
    float*  colsum = (float*)(ws + (12 << 20));              // 64 KB
    bf16_t* Pt     = (bf16_t*)(ws + (17 << 20));             // 64 MB
    bf16_t* WT     = (bf16_t*)(ws + (81 << 20));             // 32 KB
    bf16_t* AT     = (bf16_t*)(ws + (81 << 20) + (32 << 10));// 32 KB

    hipMemsetAsync(colsum, 0, B_ * N_ * sizeof(float), stream);
    k_prep<<<64, 256, 0, stream>>>(Ww, Aw, WT, AT);
    k_hg<<<B_ * N_ / 64, 256, 0, stream>>>(x, Wb, WT, AT, hb, gb);
    k_att<<<2048, 256, 0, stream>>>(hb, gb, adj, colsum, Pt);
    k_scaleT<<<512, 256, 0, stream>>>(hb, colsum, hbTs);
    k_out<<<256, 512, 0, stream>>>(Pt, hbTs, x, gw, gbias, out);
}